// Round 9
// baseline (819.945 us; speedup 1.0000x reference)
//
#include <hip/hip_runtime.h>

// ---------------------------------------------------------------------------
// BEV encoder: bucketed points->BEV (LDS-aggregated) + 3x conv-BN-ReLU
// Conv v6 = round-5 geometry (16x16 tile, 1 px/thread, OCG=16 SGPR weights)
// + T14 async-STAGE double-buffer (reg prefetch hides phase staging latency)
// + LDS row pad 18->19 (bank conflicts) + fused BN staging + epilogue f64
// BN partials (no separate bnstats passes).
// ---------------------------------------------------------------------------

constexpr int BEVW = 250;
constexpr int SZC  = BEVW * BEVW;     // 62500 cells
constexpr int NB   = 512;             // blocks in bucket pass
constexpr int PPT  = 16;              // points/thread/chunk
constexpr int CHUNK = 256 * PPT;      // 4096
constexpr int NBKT = 100;             // 10x10 tiles of 25x25 cells
constexpr int NCELL = 625;            // cells per bucket
constexpr int CAPB = 43008;           // records capacity per bucket
constexpr int NTILE = 256;            // 16x16 conv tiles of 16x16

__device__ __forceinline__ unsigned f2ord(float f) {
    unsigned u = __float_as_uint(f);
    return (u & 0x80000000u) ? ~u : (u | 0x80000000u);
}
__device__ __forceinline__ float ord2f(unsigned u) {
    unsigned b = (u & 0x80000000u) ? (u & 0x7FFFFFFFu) : ~u;
    return __uint_as_float(b);
}

// ---- zero bucket counters ------------------------------------------------
__global__ void k_initg(unsigned* __restrict__ gcnt) {
    if (threadIdx.x < 128) gcnt[threadIdx.x] = 0u;
}

// ---- pass B: bin points into bucket record arrays ------------------------
// rec = z_ord(32) | cell_local(10) | inten_q22(22)
__launch_bounds__(256)
__global__ void k_bucket(const float4* __restrict__ pts, int n,
                         unsigned long long* __restrict__ recs,
                         unsigned* __restrict__ gcnt) {
    __shared__ unsigned lcnt[NBKT];
    __shared__ unsigned lbase[NBKT];
    const int tid = threadIdx.x;
    if (tid < NBKT) lcnt[tid] = 0u;
    __syncthreads();

    const int ppb = (n + NB - 1) / NB;
    const int start = blockIdx.x * ppb;
    const int end = min(start + ppb, n);

    for (int c0 = start; c0 < end; c0 += CHUNK) {
        unsigned long long rec[PPT];
        int bkt[PPT];
        unsigned slot[PPT];
        unsigned vmask = 0u;
#pragma unroll
        for (int k = 0; k < PPT; ++k) {
            int p = c0 + k * 256 + tid;
            if (p >= end) continue;
            float4 q = pts[p];
            if (!(q.x >= -50.0f && q.x < 50.0f && q.y >= -50.0f && q.y < 50.0f))
                continue;
            // must match JAX/np f32 semantics: f32 add, f32 div, trunc, clip
            int xi = (int)((q.x + 50.0f) / 0.4f);
            int yi = (int)((q.y + 50.0f) / 0.4f);
            xi = min(max(xi, 0), BEVW - 1);
            yi = min(max(yi, 0), BEVW - 1);
            int b  = (yi / 25) * 10 + (xi / 25);
            int cl = (yi % 25) * 25 + (xi % 25);
            unsigned iq = (unsigned)(q.w * 4194304.0f);   // 2^22, q.w in [0,1)
            rec[k] = ((unsigned long long)f2ord(q.z) << 32) |
                     ((unsigned long long)(unsigned)cl << 22) | iq;
            bkt[k] = b;
            slot[k] = atomicAdd(&lcnt[b], 1u);
            vmask |= 1u << k;
        }
        __syncthreads();
        if (tid < NBKT) {
            unsigned c = lcnt[tid];
            if (c) lbase[tid] = atomicAdd(&gcnt[tid], c);
            lcnt[tid] = 0u;
        }
        __syncthreads();
#pragma unroll
        for (int k = 0; k < PPT; ++k) {
            if (!((vmask >> k) & 1u)) continue;
            unsigned idx = lbase[bkt[k]] + slot[k];
            if (idx < (unsigned)CAPB)
                recs[(size_t)bkt[k] * CAPB + idx] = rec[k];
        }
    }
}

// ---- pass C: per-bucket LDS reduction + fused finalize -------------------
__launch_bounds__(1024)
__global__ void k_reduce(const unsigned long long* __restrict__ recs,
                         const unsigned* __restrict__ gcnt,
                         float* __restrict__ bev) {
    __shared__ unsigned mxA[NCELL], mnA[NCELL], ctA[NCELL], siA[NCELL];
    const int b = blockIdx.x;
    for (int i = threadIdx.x; i < NCELL; i += 1024) {
        mxA[i] = 0u; mnA[i] = 0xFFFFFFFFu; ctA[i] = 0u; siA[i] = 0u;
    }
    __syncthreads();
    const unsigned nb = min(gcnt[b], (unsigned)CAPB);
    const unsigned long long* rb = recs + (size_t)b * CAPB;
    for (unsigned i = threadIdx.x; i < nb; i += 1024) {
        unsigned long long r = rb[i];
        unsigned zo = (unsigned)(r >> 32);
        unsigned cl = ((unsigned)(r >> 22)) & 0x3FFu;
        unsigned iq = (unsigned)r & 0x3FFFFFu;
        atomicMax(&mxA[cl], zo);
        atomicMin(&mnA[cl], zo);
        atomicAdd(&ctA[cl], 1u);
        atomicAdd(&siA[cl], iq);
    }
    __syncthreads();
    const int tx = b % 10, ty = b / 10;
    for (int i = threadIdx.x; i < NCELL; i += 1024) {
        int cy = ty * 25 + i / 25, cx = tx * 25 + i % 25;
        int cell = cy * BEVW + cx;
        unsigned c = ctA[i];
        bool has = c > 0u;
        float dn = (float)c;
        float isum = (float)siA[i] * (1.0f / 4194304.0f);
        bev[0 * SZC + cell] = has ? ord2f(mxA[i]) : 0.0f;
        bev[1 * SZC + cell] = has ? ord2f(mnA[i]) : 0.0f;
        bev[2 * SZC + cell] = log1pf(dn);
        bev[3 * SZC + cell] = has ? isum / dn : 0.0f;
    }
}

// ---- weight transpose: w[oc][ic][3][3] -> wt[ic][k][oc] ------------------
__global__ void k_wt(const float* __restrict__ w, float* __restrict__ wt,
                     int CIN, int COUT) {
    int i = blockIdx.x * blockDim.x + threadIdx.x;
    if (i >= COUT * CIN * 9) return;
    int oc = i / (CIN * 9);
    int r  = i % (CIN * 9);
    int ic = r / 9, k = r % 9;
    wt[(ic * 9 + k) * COUT + oc] = w[i];
}

// ---- conv 3x3 SAME, 16x16 tile, 1 px/thread, SGPR weights, dbuf LDS ------
// in: [CIN][250][250] raw prev conv out (BN+ReLU via ab[] if FUSE),
// wt: [CIN][9][COUT], out: conv+bias. bnpart[(oc*NTILE+tile)*2+{0,1}] gets
// this block's f64 {sum, sumsq} over its valid outputs (deterministic).
template <int CIN, int COUT, int ICB, int OCG, bool FUSE>
__launch_bounds__(256)
__global__ void k_conv(const float* __restrict__ in, const float* __restrict__ wt,
                       const float* __restrict__ bias, const float* __restrict__ ab,
                       float* __restrict__ out, double* __restrict__ bnpart) {
    constexpr int PH = CIN / ICB;             // staging phases
    constexpr int RS = 19;                    // padded row stride (banks)
    constexpr int CSZ = 18 * RS;              // floats per channel slice
    constexpr int TE = ICB * 324;             // logical elems per phase
    constexpr int NJ = (TE + 255) / 256;      // loads per thread per phase
    __shared__ float s_in[2][ICB][CSZ];
    __shared__ double s_red[4][OCG][2];

    const int tid = threadIdx.x;
    const int u = tid & 15, v = tid >> 4;
    const int tile = blockIdx.x;              // 0..255
    const int tx = (tile & 15) * 16, ty = (tile >> 4) * 16;
    const int oc0 = blockIdx.y * OCG;
    const int lane = tid & 63, wid = tid >> 6;

    float acc[OCG];
#pragma unroll
    for (int o = 0; o < OCG; ++o) acc[o] = 0.0f;

    // ---- prologue: stage phase 0 into buffer 0
#pragma unroll
    for (int j = 0; j < NJ; ++j) {
        int e = j * 256 + tid;
        if (e < TE) {
            int c = e / 324, rem = e % 324;
            int r = rem / 18, q = rem % 18;
            int gy = ty - 1 + r, gx = tx - 1 + q;
            float x = 0.0f;
            if (gy >= 0 && gy < BEVW && gx >= 0 && gx < BEVW) {
                x = in[(size_t)c * SZC + gy * BEVW + gx];
                if (FUSE) x = fmaxf(fmaf(x, ab[2 * c], ab[2 * c + 1]), 0.0f);
            }
            s_in[0][c][r * RS + q] = x;
        }
    }
    __syncthreads();

#pragma unroll 1
    for (int t = 0; t < PH; ++t) {
        const int cur = t & 1;

        // T14: issue next-phase global loads into regs BEFORE compute
        float rv[NJ];
        if (t + 1 < PH) {
            const int icn = (t + 1) * ICB;
#pragma unroll
            for (int j = 0; j < NJ; ++j) {
                int e = j * 256 + tid;
                rv[j] = 0.0f;
                if (e < TE) {
                    int c = e / 324, rem = e % 324;
                    int r = rem / 18, q = rem % 18;
                    int gy = ty - 1 + r, gx = tx - 1 + q;
                    if (gy >= 0 && gy < BEVW && gx >= 0 && gx < BEVW) {
                        int cg = icn + c;
                        float x = in[(size_t)cg * SZC + gy * BEVW + gx];
                        if (FUSE) x = fmaxf(fmaf(x, ab[2 * cg], ab[2 * cg + 1]), 0.0f);
                        rv[j] = x;
                    }
                }
            }
        }

        // compute on s_in[cur] (~ICB*9*OCG FMAs — hides the loads above)
#pragma unroll
        for (int icl = 0; icl < ICB; ++icl) {
            const int icg = t * ICB + icl;
#pragma unroll
            for (int tap = 0; tap < 9; ++tap) {
                const int ky = tap / 3, kx = tap % 3;
                float x = s_in[cur][icl][(v + ky) * RS + u + kx];
                // block-uniform address -> scalar loads into SGPRs
                const float* wk = wt + ((size_t)(icg * 9 + tap) * COUT + oc0);
#pragma unroll
                for (int o = 0; o < OCG; ++o)
                    acc[o] = fmaf(x, wk[o], acc[o]);
            }
        }

        // publish prefetched phase into the other buffer
        if (t + 1 < PH) {
#pragma unroll
            for (int j = 0; j < NJ; ++j) {
                int e = j * 256 + tid;
                if (e < TE) {
                    int c = e / 324, rem = e % 324;
                    s_in[cur ^ 1][c][(rem / 18) * RS + rem % 18] = rv[j];
                }
            }
        }
        __syncthreads();
    }

    // ---- epilogue: bias, store, f64 BN partials (deterministic)
    const int ox = tx + u, oy = ty + v;
    const bool valid = (ox < BEVW) && (oy < BEVW);
#pragma unroll
    for (int o = 0; o < OCG; ++o) {
        float y = acc[o] + bias[oc0 + o];
        if (valid) out[(size_t)(oc0 + o) * SZC + oy * BEVW + ox] = y;
        double s = valid ? (double)y : 0.0;
        double s2 = valid ? (double)y * (double)y : 0.0;
#pragma unroll
        for (int off = 32; off; off >>= 1) {
            s  += __shfl_down(s, off);
            s2 += __shfl_down(s2, off);
        }
        if (lane == 0) { s_red[wid][o][0] = s; s_red[wid][o][1] = s2; }
    }
    __syncthreads();
    if (tid < OCG) {
        double S = 0.0, S2 = 0.0;
#pragma unroll
        for (int wv = 0; wv < 4; ++wv) { S += s_red[wv][tid][0]; S2 += s_red[wv][tid][1]; }
        bnpart[((size_t)(oc0 + tid) * NTILE + tile) * 2]     = S;
        bnpart[((size_t)(oc0 + tid) * NTILE + tile) * 2 + 1] = S2;
    }
}

// ---- BN stats stage 2: fold tile partials -> (A,B) affine ----------------
// statsAB[2c] = rs*g, statsAB[2c+1] = beta - mu*rs*g ; BN+ReLU = relu(A*x+B)
__global__ void k_bnstats2(const double* __restrict__ part, const float* __restrict__ g,
                           const float* __restrict__ beta, float* __restrict__ statsAB) {
    int c = threadIdx.x;
    double S = 0.0, S2 = 0.0;
    for (int t = 0; t < NTILE; ++t) {
        S  += part[((size_t)c * NTILE + t) * 2];
        S2 += part[((size_t)c * NTILE + t) * 2 + 1];
    }
    double mu  = S / (double)SZC;
    double var = S2 / (double)SZC - mu * mu;
    double A = (1.0 / sqrt(var + 1e-5)) * (double)g[c];
    statsAB[2 * c]     = (float)A;
    statsAB[2 * c + 1] = (float)((double)beta[c] - mu * A);
}

// ---- final BN apply + ReLU ----------------------------------------------
__global__ void k_bnreluS(const float* __restrict__ y, const float* __restrict__ ab,
                          float* __restrict__ out) {
    int c = blockIdx.y;
    int i = blockIdx.x * blockDim.x + threadIdx.x;
    if (i >= SZC) return;
    size_t idx = (size_t)c * SZC + i;
    out[idx] = fmaxf(fmaf(y[idx], ab[2 * c], ab[2 * c + 1]), 0.0f);
}

// ---------------------------------------------------------------------------
extern "C" void kernel_launch(void* const* d_in, const int* in_sizes, int n_in,
                              void* d_out, int out_size, void* d_ws, size_t ws_size,
                              hipStream_t stream) {
    const float4* pts = (const float4*)d_in[0];
    const float* w1 = (const float*)d_in[1];
    const float* b1 = (const float*)d_in[2];
    const float* g1 = (const float*)d_in[3];
    const float* be1 = (const float*)d_in[4];
    const float* w2 = (const float*)d_in[5];
    const float* b2 = (const float*)d_in[6];
    const float* g2 = (const float*)d_in[7];
    const float* be2 = (const float*)d_in[8];
    const float* w3 = (const float*)d_in[9];
    const float* b3 = (const float*)d_in[10];
    const float* g3 = (const float*)d_in[11];
    const float* be3 = (const float*)d_in[12];

    float* ws = (float*)d_ws;
    const size_t wsf = ws_size / 4;

    // --- fixed tail at end of workspace ---
    // bnpart: 64*NTILE*2 doubles = 65536 floats
    constexpr size_t TAILF = 128 + 250000 + 64 + 128 + 128 + 65536 + 1152 + 18432 + 36864;
    float* tail = ws + (wsf - TAILF);
    unsigned* gcnt = (unsigned*)tail;
    float* bev = tail + 128;                  // 4*SZC
    float* st1 = bev + 4 * SZC;               // 64  (A,B per ch)
    float* st2 = st1 + 64;                    // 128
    float* st3 = st2 + 128;                   // 128
    double* bnpart = (double*)(st3 + 128);    // 64*256*2 doubles
    float* wt1 = st3 + 128 + 65536;           // 1152
    float* wt2 = wt1 + 1152;                  // 18432
    float* wt3 = wt2 + 18432;                 // 36864

    // --- dynamic region: recs, then activations alias (recs dead) ---
    unsigned long long* recs = (unsigned long long*)ws;   // 8,601,600 floats
    float* y1 = ws;                                       // 32*SZC
    float* y2 = ws + 2000000;                             // 64*SZC
    float* out = (float*)d_out;

    int n = in_sizes[0] / 4;                              // 5,000,000 points
    const int cellBlocks = (SZC + 255) / 256;

    // weight transposes
    k_wt<<<(32 * 4 * 9 + 255) / 256, 256, 0, stream>>>(w1, wt1, 4, 32);
    k_wt<<<(64 * 32 * 9 + 255) / 256, 256, 0, stream>>>(w2, wt2, 32, 64);
    k_wt<<<(64 * 64 * 9 + 255) / 256, 256, 0, stream>>>(w3, wt3, 64, 64);

    // points -> BEV
    k_initg<<<1, 128, 0, stream>>>(gcnt);
    k_bucket<<<NB, 256, 0, stream>>>(pts, n, recs, gcnt);
    k_reduce<<<NBKT, 1024, 0, stream>>>(recs, gcnt, bev);

    // layer 1: 4 -> 32 (raw conv out; BN1 fused into conv2 staging)
    k_conv<4, 32, 4, 16, false><<<dim3(NTILE, 2), 256, 0, stream>>>(bev, wt1, b1, nullptr, y1, bnpart);
    k_bnstats2<<<1, 32, 0, stream>>>(bnpart, g1, be1, st1);

    // layer 2: 32 -> 64 (BN1+ReLU fused into staging)
    k_conv<32, 64, 8, 16, true><<<dim3(NTILE, 4), 256, 0, stream>>>(y1, wt2, b2, st1, y2, bnpart);
    k_bnstats2<<<1, 64, 0, stream>>>(bnpart, g2, be2, st2);

    // layer 3: 64 -> 64 (BN2+ReLU fused into staging; raw out -> d_out)
    k_conv<64, 64, 8, 16, true><<<dim3(NTILE, 4), 256, 0, stream>>>(y2, wt3, b3, st2, out, bnpart);
    k_bnstats2<<<1, 64, 0, stream>>>(bnpart, g3, be3, st3);

    // final BN3 + ReLU in place
    k_bnreluS<<<dim3(cellBlocks, 64), 256, 0, stream>>>(out, st3, out);
}

// Round 10
// 351.054 us; speedup vs baseline: 2.3357x; 2.3357x over previous
//
#include <hip/hip_runtime.h>

// ---------------------------------------------------------------------------
// BEV encoder: bucketed points->BEV (LDS-aggregated) + 3x conv-BN-ReLU
// Conv v7 = EXACT round-5 conv structure (16x16 tile, 1 px/thread, OCG=16
// SGPR weights, simple stage/barrier/compute, minimal VGPR+LDS) + round-8's
// validated fusions (BN+ReLU in staging, epilogue f64 BN partials).
// Lesson r6/r7/r9: this conv wants minimal footprint, not pipelining.
// ---------------------------------------------------------------------------

constexpr int BEVW = 250;
constexpr int SZC  = BEVW * BEVW;     // 62500 cells
constexpr int NB   = 512;             // blocks in bucket pass
constexpr int PPT  = 16;              // points/thread/chunk
constexpr int CHUNK = 256 * PPT;      // 4096
constexpr int NBKT = 100;             // 10x10 tiles of 25x25 cells
constexpr int NCELL = 625;            // cells per bucket
constexpr int CAPB = 43008;           // records capacity per bucket
constexpr int NTILE = 256;            // 16x16 conv tiles of 16x16

__device__ __forceinline__ unsigned f2ord(float f) {
    unsigned u = __float_as_uint(f);
    return (u & 0x80000000u) ? ~u : (u | 0x80000000u);
}
__device__ __forceinline__ float ord2f(unsigned u) {
    unsigned b = (u & 0x80000000u) ? (u & 0x7FFFFFFFu) : ~u;
    return __uint_as_float(b);
}

// ---- zero bucket counters ------------------------------------------------
__global__ void k_initg(unsigned* __restrict__ gcnt) {
    if (threadIdx.x < 128) gcnt[threadIdx.x] = 0u;
}

// ---- pass B: bin points into bucket record arrays ------------------------
// rec = z_ord(32) | cell_local(10) | inten_q22(22)
__launch_bounds__(256)
__global__ void k_bucket(const float4* __restrict__ pts, int n,
                         unsigned long long* __restrict__ recs,
                         unsigned* __restrict__ gcnt) {
    __shared__ unsigned lcnt[NBKT];
    __shared__ unsigned lbase[NBKT];
    const int tid = threadIdx.x;
    if (tid < NBKT) lcnt[tid] = 0u;
    __syncthreads();

    const int ppb = (n + NB - 1) / NB;
    const int start = blockIdx.x * ppb;
    const int end = min(start + ppb, n);

    for (int c0 = start; c0 < end; c0 += CHUNK) {
        unsigned long long rec[PPT];
        int bkt[PPT];
        unsigned slot[PPT];
        unsigned vmask = 0u;
#pragma unroll
        for (int k = 0; k < PPT; ++k) {
            int p = c0 + k * 256 + tid;
            if (p >= end) continue;
            float4 q = pts[p];
            if (!(q.x >= -50.0f && q.x < 50.0f && q.y >= -50.0f && q.y < 50.0f))
                continue;
            // must match JAX/np f32 semantics: f32 add, f32 div, trunc, clip
            int xi = (int)((q.x + 50.0f) / 0.4f);
            int yi = (int)((q.y + 50.0f) / 0.4f);
            xi = min(max(xi, 0), BEVW - 1);
            yi = min(max(yi, 0), BEVW - 1);
            int b  = (yi / 25) * 10 + (xi / 25);
            int cl = (yi % 25) * 25 + (xi % 25);
            unsigned iq = (unsigned)(q.w * 4194304.0f);   // 2^22, q.w in [0,1)
            rec[k] = ((unsigned long long)f2ord(q.z) << 32) |
                     ((unsigned long long)(unsigned)cl << 22) | iq;
            bkt[k] = b;
            slot[k] = atomicAdd(&lcnt[b], 1u);
            vmask |= 1u << k;
        }
        __syncthreads();
        if (tid < NBKT) {
            unsigned c = lcnt[tid];
            if (c) lbase[tid] = atomicAdd(&gcnt[tid], c);
            lcnt[tid] = 0u;
        }
        __syncthreads();
#pragma unroll
        for (int k = 0; k < PPT; ++k) {
            if (!((vmask >> k) & 1u)) continue;
            unsigned idx = lbase[bkt[k]] + slot[k];
            if (idx < (unsigned)CAPB)
                recs[(size_t)bkt[k] * CAPB + idx] = rec[k];
        }
    }
}

// ---- pass C: per-bucket LDS reduction + fused finalize -------------------
__launch_bounds__(1024)
__global__ void k_reduce(const unsigned long long* __restrict__ recs,
                         const unsigned* __restrict__ gcnt,
                         float* __restrict__ bev) {
    __shared__ unsigned mxA[NCELL], mnA[NCELL], ctA[NCELL], siA[NCELL];
    const int b = blockIdx.x;
    for (int i = threadIdx.x; i < NCELL; i += 1024) {
        mxA[i] = 0u; mnA[i] = 0xFFFFFFFFu; ctA[i] = 0u; siA[i] = 0u;
    }
    __syncthreads();
    const unsigned nb = min(gcnt[b], (unsigned)CAPB);
    const unsigned long long* rb = recs + (size_t)b * CAPB;
    for (unsigned i = threadIdx.x; i < nb; i += 1024) {
        unsigned long long r = rb[i];
        unsigned zo = (unsigned)(r >> 32);
        unsigned cl = ((unsigned)(r >> 22)) & 0x3FFu;
        unsigned iq = (unsigned)r & 0x3FFFFFu;
        atomicMax(&mxA[cl], zo);
        atomicMin(&mnA[cl], zo);
        atomicAdd(&ctA[cl], 1u);
        atomicAdd(&siA[cl], iq);
    }
    __syncthreads();
    const int tx = b % 10, ty = b / 10;
    for (int i = threadIdx.x; i < NCELL; i += 1024) {
        int cy = ty * 25 + i / 25, cx = tx * 25 + i % 25;
        int cell = cy * BEVW + cx;
        unsigned c = ctA[i];
        bool has = c > 0u;
        float dn = (float)c;
        float isum = (float)siA[i] * (1.0f / 4194304.0f);
        bev[0 * SZC + cell] = has ? ord2f(mxA[i]) : 0.0f;
        bev[1 * SZC + cell] = has ? ord2f(mnA[i]) : 0.0f;
        bev[2 * SZC + cell] = log1pf(dn);
        bev[3 * SZC + cell] = has ? isum / dn : 0.0f;
    }
}

// ---- weight transpose: w[oc][ic][3][3] -> wt[ic][k][oc] ------------------
__global__ void k_wt(const float* __restrict__ w, float* __restrict__ wt,
                     int CIN, int COUT) {
    int i = blockIdx.x * blockDim.x + threadIdx.x;
    if (i >= COUT * CIN * 9) return;
    int oc = i / (CIN * 9);
    int r  = i % (CIN * 9);
    int ic = r / 9, k = r % 9;
    wt[(ic * 9 + k) * COUT + oc] = w[i];
}

// ---- conv 3x3 SAME, 16x16 tile, 1 px/thread, SGPR weights ----------------
// in: [CIN][250][250] raw prev conv out (BN+ReLU via ab[] if FUSE),
// wt: [CIN][9][COUT], out: conv+bias. bnpart[(oc*NTILE+tile)*2+{0,1}] gets
// this block's f64 {sum, sumsq} over its valid outputs (deterministic).
template <int CIN, int COUT, int ICB, int OCG, bool FUSE>
__launch_bounds__(256)
__global__ void k_conv(const float* __restrict__ in, const float* __restrict__ wt,
                       const float* __restrict__ bias, const float* __restrict__ ab,
                       float* __restrict__ out, double* __restrict__ bnpart) {
    __shared__ float s_in[ICB][18 * 18];
    __shared__ double s_red[4][OCG][2];

    const int tid = threadIdx.x;
    const int u = tid & 15, v = tid >> 4;
    const int tile = blockIdx.x;              // 0..255
    const int tx = (tile & 15) * 16, ty = (tile >> 4) * 16;
    const int oc0 = blockIdx.y * OCG;
    const int lane = tid & 63, wid = tid >> 6;

    float acc[OCG];
#pragma unroll
    for (int o = 0; o < OCG; ++o) acc[o] = 0.0f;

    for (int ic0 = 0; ic0 < CIN; ic0 += ICB) {
        __syncthreads();
        // stage input tile with halo; fused prev-layer BN+ReLU
        for (int e = tid; e < ICB * 324; e += 256) {
            int c = e / 324, rem = e % 324;
            int r = rem / 18, q = rem % 18;
            int cg = ic0 + c;
            int gy = ty - 1 + r, gx = tx - 1 + q;
            float x = 0.0f;
            if (gy >= 0 && gy < BEVW && gx >= 0 && gx < BEVW) {
                x = in[(size_t)cg * SZC + gy * BEVW + gx];
                if (FUSE) x = fmaxf(fmaf(x, ab[2 * cg], ab[2 * cg + 1]), 0.0f);
            }
            s_in[c][rem] = x;
        }
        __syncthreads();

#pragma unroll
        for (int icl = 0; icl < ICB; ++icl) {
            const int icg = ic0 + icl;
#pragma unroll
            for (int tap = 0; tap < 9; ++tap) {
                const int ky = tap / 3, kx = tap % 3;
                float x = s_in[icl][(v + ky) * 18 + u + kx];
                // block-uniform address -> scalar loads into SGPRs
                const float* wk = wt + ((size_t)(icg * 9 + tap) * COUT + oc0);
#pragma unroll
                for (int o = 0; o < OCG; ++o)
                    acc[o] = fmaf(x, wk[o], acc[o]);
            }
        }
    }

    // ---- epilogue: bias, store, f64 BN partials (deterministic)
    const int ox = tx + u, oy = ty + v;
    const bool valid = (ox < BEVW) && (oy < BEVW);
#pragma unroll
    for (int o = 0; o < OCG; ++o) {
        float y = acc[o] + bias[oc0 + o];
        if (valid) out[(size_t)(oc0 + o) * SZC + oy * BEVW + ox] = y;
        double s = valid ? (double)y : 0.0;
        double s2 = valid ? (double)y * (double)y : 0.0;
#pragma unroll
        for (int off = 32; off; off >>= 1) {
            s  += __shfl_down(s, off);
            s2 += __shfl_down(s2, off);
        }
        if (lane == 0) { s_red[wid][o][0] = s; s_red[wid][o][1] = s2; }
    }
    __syncthreads();
    if (tid < OCG) {
        double S = 0.0, S2 = 0.0;
#pragma unroll
        for (int wv = 0; wv < 4; ++wv) { S += s_red[wv][tid][0]; S2 += s_red[wv][tid][1]; }
        bnpart[((size_t)(oc0 + tid) * NTILE + tile) * 2]     = S;
        bnpart[((size_t)(oc0 + tid) * NTILE + tile) * 2 + 1] = S2;
    }
}

// ---- BN stats stage 2: fold tile partials -> (A,B) affine ----------------
// statsAB[2c] = rs*g, statsAB[2c+1] = beta - mu*rs*g ; BN+ReLU = relu(A*x+B)
__global__ void k_bnstats2(const double* __restrict__ part, const float* __restrict__ g,
                           const float* __restrict__ beta, float* __restrict__ statsAB) {
    int c = threadIdx.x;
    double S = 0.0, S2 = 0.0;
    for (int t = 0; t < NTILE; ++t) {
        S  += part[((size_t)c * NTILE + t) * 2];
        S2 += part[((size_t)c * NTILE + t) * 2 + 1];
    }
    double mu  = S / (double)SZC;
    double var = S2 / (double)SZC - mu * mu;
    double A = (1.0 / sqrt(var + 1e-5)) * (double)g[c];
    statsAB[2 * c]     = (float)A;
    statsAB[2 * c + 1] = (float)((double)beta[c] - mu * A);
}

// ---- final BN apply + ReLU ----------------------------------------------
__global__ void k_bnreluS(const float* __restrict__ y, const float* __restrict__ ab,
                          float* __restrict__ out) {
    int c = blockIdx.y;
    int i = blockIdx.x * blockDim.x + threadIdx.x;
    if (i >= SZC) return;
    size_t idx = (size_t)c * SZC + i;
    out[idx] = fmaxf(fmaf(y[idx], ab[2 * c], ab[2 * c + 1]), 0.0f);
}

// ---------------------------------------------------------------------------
extern "C" void kernel_launch(void* const* d_in, const int* in_sizes, int n_in,
                              void* d_out, int out_size, void* d_ws, size_t ws_size,
                              hipStream_t stream) {
    const float4* pts = (const float4*)d_in[0];
    const float* w1 = (const float*)d_in[1];
    const float* b1 = (const float*)d_in[2];
    const float* g1 = (const float*)d_in[3];
    const float* be1 = (const float*)d_in[4];
    const float* w2 = (const float*)d_in[5];
    const float* b2 = (const float*)d_in[6];
    const float* g2 = (const float*)d_in[7];
    const float* be2 = (const float*)d_in[8];
    const float* w3 = (const float*)d_in[9];
    const float* b3 = (const float*)d_in[10];
    const float* g3 = (const float*)d_in[11];
    const float* be3 = (const float*)d_in[12];

    float* ws = (float*)d_ws;
    const size_t wsf = ws_size / 4;

    // --- fixed tail at end of workspace ---
    // bnpart: 64*NTILE*2 doubles = 65536 floats
    constexpr size_t TAILF = 128 + 250000 + 64 + 128 + 128 + 65536 + 1152 + 18432 + 36864;
    float* tail = ws + (wsf - TAILF);
    unsigned* gcnt = (unsigned*)tail;
    float* bev = tail + 128;                  // 4*SZC
    float* st1 = bev + 4 * SZC;               // 64  (A,B per ch)
    float* st2 = st1 + 64;                    // 128
    float* st3 = st2 + 128;                   // 128
    double* bnpart = (double*)(st3 + 128);    // 64*256*2 doubles
    float* wt1 = st3 + 128 + 65536;           // 1152
    float* wt2 = wt1 + 1152;                  // 18432
    float* wt3 = wt2 + 18432;                 // 36864

    // --- dynamic region: recs, then activations alias (recs dead) ---
    unsigned long long* recs = (unsigned long long*)ws;   // 8,601,600 floats
    float* y1 = ws;                                       // 32*SZC
    float* y2 = ws + 2000000;                             // 64*SZC
    float* out = (float*)d_out;

    int n = in_sizes[0] / 4;                              // 5,000,000 points
    const int cellBlocks = (SZC + 255) / 256;

    // weight transposes
    k_wt<<<(32 * 4 * 9 + 255) / 256, 256, 0, stream>>>(w1, wt1, 4, 32);
    k_wt<<<(64 * 32 * 9 + 255) / 256, 256, 0, stream>>>(w2, wt2, 32, 64);
    k_wt<<<(64 * 64 * 9 + 255) / 256, 256, 0, stream>>>(w3, wt3, 64, 64);

    // points -> BEV
    k_initg<<<1, 128, 0, stream>>>(gcnt);
    k_bucket<<<NB, 256, 0, stream>>>(pts, n, recs, gcnt);
    k_reduce<<<NBKT, 1024, 0, stream>>>(recs, gcnt, bev);

    // layer 1: 4 -> 32 (raw conv out; BN1 fused into conv2 staging)
    k_conv<4, 32, 4, 16, false><<<dim3(NTILE, 2), 256, 0, stream>>>(bev, wt1, b1, nullptr, y1, bnpart);
    k_bnstats2<<<1, 32, 0, stream>>>(bnpart, g1, be1, st1);

    // layer 2: 32 -> 64 (BN1+ReLU fused into staging)
    k_conv<32, 64, 8, 16, true><<<dim3(NTILE, 4), 256, 0, stream>>>(y1, wt2, b2, st1, y2, bnpart);
    k_bnstats2<<<1, 64, 0, stream>>>(bnpart, g2, be2, st2);

    // layer 3: 64 -> 64 (BN2+ReLU fused into staging; raw out -> d_out)
    k_conv<64, 64, 8, 16, true><<<dim3(NTILE, 4), 256, 0, stream>>>(y2, wt3, b3, st2, out, bnpart);
    k_bnstats2<<<1, 64, 0, stream>>>(bnpart, g3, be3, st3);

    // final BN3 + ReLU in place
    k_bnreluS<<<dim3(cellBlocks, 64), 256, 0, stream>>>(out, st3, out);
}

// Round 12
// 288.534 us; speedup vs baseline: 2.8418x; 1.2167x over previous
//
#include <hip/hip_runtime.h>

// ---------------------------------------------------------------------------
// BEV encoder: bucketed points->BEV (LDS-aggregated) + 3x conv-BN-ReLU
// Conv v9 = r5's measured-best conv verbatim (16x16 tile, 1 px/thread,
// OCG=16 SGPR weights, simple stage/barrier/compute, minimal VGPR) with
// BN+ReLU of the prev layer fused into STAGING (2 VALU/elem, no extra VGPR),
// r5's two-stage BN stats, and a single final BN+ReLU pass.
// Lessons r6/r7/r9/r11: do not complicate the conv inner loop.
// ---------------------------------------------------------------------------

constexpr int BEVW = 250;
constexpr int SZC  = BEVW * BEVW;     // 62500 cells
constexpr int NB   = 512;             // blocks in bucket pass
constexpr int PPT  = 16;              // points/thread/chunk
constexpr int CHUNK = 256 * PPT;      // 4096
constexpr int NBKT = 100;             // 10x10 tiles of 25x25 cells
constexpr int NCELL = 625;            // cells per bucket
constexpr int CAPB = 43008;           // records capacity per bucket
constexpr int NSL  = 8;               // bnstats slices per channel

__device__ __forceinline__ unsigned f2ord(float f) {
    unsigned u = __float_as_uint(f);
    return (u & 0x80000000u) ? ~u : (u | 0x80000000u);
}
__device__ __forceinline__ float ord2f(unsigned u) {
    unsigned b = (u & 0x80000000u) ? (u & 0x7FFFFFFFu) : ~u;
    return __uint_as_float(b);
}

// ---- zero bucket counters ------------------------------------------------
__global__ void k_initg(unsigned* __restrict__ gcnt) {
    if (threadIdx.x < 128) gcnt[threadIdx.x] = 0u;
}

// ---- pass B: bin points into bucket record arrays ------------------------
// rec = z_ord(32) | cell_local(10) | inten_q22(22)
__launch_bounds__(256)
__global__ void k_bucket(const float4* __restrict__ pts, int n,
                         unsigned long long* __restrict__ recs,
                         unsigned* __restrict__ gcnt) {
    __shared__ unsigned lcnt[NBKT];
    __shared__ unsigned lbase[NBKT];
    const int tid = threadIdx.x;
    if (tid < NBKT) lcnt[tid] = 0u;
    __syncthreads();

    const int ppb = (n + NB - 1) / NB;
    const int start = blockIdx.x * ppb;
    const int end = min(start + ppb, n);

    for (int c0 = start; c0 < end; c0 += CHUNK) {
        unsigned long long rec[PPT];
        int bkt[PPT];
        unsigned slot[PPT];
        unsigned vmask = 0u;
#pragma unroll
        for (int k = 0; k < PPT; ++k) {
            int p = c0 + k * 256 + tid;
            if (p >= end) continue;
            float4 q = pts[p];
            if (!(q.x >= -50.0f && q.x < 50.0f && q.y >= -50.0f && q.y < 50.0f))
                continue;
            // must match JAX/np f32 semantics: f32 add, f32 div, trunc, clip
            int xi = (int)((q.x + 50.0f) / 0.4f);
            int yi = (int)((q.y + 50.0f) / 0.4f);
            xi = min(max(xi, 0), BEVW - 1);
            yi = min(max(yi, 0), BEVW - 1);
            int b  = (yi / 25) * 10 + (xi / 25);
            int cl = (yi % 25) * 25 + (xi % 25);
            unsigned iq = (unsigned)(q.w * 4194304.0f);   // 2^22, q.w in [0,1)
            rec[k] = ((unsigned long long)f2ord(q.z) << 32) |
                     ((unsigned long long)(unsigned)cl << 22) | iq;
            bkt[k] = b;
            slot[k] = atomicAdd(&lcnt[b], 1u);
            vmask |= 1u << k;
        }
        __syncthreads();
        if (tid < NBKT) {
            unsigned c = lcnt[tid];
            if (c) lbase[tid] = atomicAdd(&gcnt[tid], c);
            lcnt[tid] = 0u;
        }
        __syncthreads();
#pragma unroll
        for (int k = 0; k < PPT; ++k) {
            if (!((vmask >> k) & 1u)) continue;
            unsigned idx = lbase[bkt[k]] + slot[k];
            if (idx < (unsigned)CAPB)
                recs[(size_t)bkt[k] * CAPB + idx] = rec[k];
        }
    }
}

// ---- pass C: per-bucket LDS reduction + fused finalize -------------------
__launch_bounds__(1024)
__global__ void k_reduce(const unsigned long long* __restrict__ recs,
                         const unsigned* __restrict__ gcnt,
                         float* __restrict__ bev) {
    __shared__ unsigned mxA[NCELL], mnA[NCELL], ctA[NCELL], siA[NCELL];
    const int b = blockIdx.x;
    for (int i = threadIdx.x; i < NCELL; i += 1024) {
        mxA[i] = 0u; mnA[i] = 0xFFFFFFFFu; ctA[i] = 0u; siA[i] = 0u;
    }
    __syncthreads();
    const unsigned nb = min(gcnt[b], (unsigned)CAPB);
    const unsigned long long* rb = recs + (size_t)b * CAPB;
    for (unsigned i = threadIdx.x; i < nb; i += 1024) {
        unsigned long long r = rb[i];
        unsigned zo = (unsigned)(r >> 32);
        unsigned cl = ((unsigned)(r >> 22)) & 0x3FFu;
        unsigned iq = (unsigned)r & 0x3FFFFFu;
        atomicMax(&mxA[cl], zo);
        atomicMin(&mnA[cl], zo);
        atomicAdd(&ctA[cl], 1u);
        atomicAdd(&siA[cl], iq);
    }
    __syncthreads();
    const int tx = b % 10, ty = b / 10;
    for (int i = threadIdx.x; i < NCELL; i += 1024) {
        int cy = ty * 25 + i / 25, cx = tx * 25 + i % 25;
        int cell = cy * BEVW + cx;
        unsigned c = ctA[i];
        bool has = c > 0u;
        float dn = (float)c;
        float isum = (float)siA[i] * (1.0f / 4194304.0f);
        bev[0 * SZC + cell] = has ? ord2f(mxA[i]) : 0.0f;
        bev[1 * SZC + cell] = has ? ord2f(mnA[i]) : 0.0f;
        bev[2 * SZC + cell] = log1pf(dn);
        bev[3 * SZC + cell] = has ? isum / dn : 0.0f;
    }
}

// ---- weight transpose: w[oc][ic][3][3] -> wt[ic][k][oc] ------------------
__global__ void k_wt(const float* __restrict__ w, float* __restrict__ wt,
                     int CIN, int COUT) {
    int i = blockIdx.x * blockDim.x + threadIdx.x;
    if (i >= COUT * CIN * 9) return;
    int oc = i / (CIN * 9);
    int r  = i % (CIN * 9);
    int ic = r / 9, k = r % 9;
    wt[(ic * 9 + k) * COUT + oc] = w[i];
}

// ---- conv 3x3 SAME, 16x16 tile, 1 px/thread, SGPR weights (r5 verbatim) --
// in: [CIN][250][250] raw prev conv out; staging applies relu(A*x+B) if FUSE
// (A,B = ab[2c],ab[2c+1]); OOB stays 0. wt: [CIN][9][COUT]. out: conv+bias.
template <int CIN, int COUT, int ICB, int OCG, bool FUSE>
__launch_bounds__(256)
__global__ void k_conv(const float* __restrict__ in, const float* __restrict__ wt,
                       const float* __restrict__ bias, const float* __restrict__ ab,
                       float* __restrict__ out) {
    __shared__ float s_in[ICB][18 * 18];

    const int tid = threadIdx.x;
    const int u = tid & 15, v = tid >> 4;
    const int tile = blockIdx.x;              // 0..255
    const int tx = (tile & 15) * 16, ty = (tile >> 4) * 16;
    const int oc0 = blockIdx.y * OCG;

    float acc[OCG];
#pragma unroll
    for (int o = 0; o < OCG; ++o) acc[o] = 0.0f;

    for (int ic0 = 0; ic0 < CIN; ic0 += ICB) {
        __syncthreads();
        // stage input tile with halo; fused prev-layer BN+ReLU (in-bounds only)
        for (int e = tid; e < ICB * 324; e += 256) {
            int c = e / 324, rem = e % 324;
            int r = rem / 18, q = rem % 18;
            int cg = ic0 + c;
            int gy = ty - 1 + r, gx = tx - 1 + q;
            float x = 0.0f;
            if (gy >= 0 && gy < BEVW && gx >= 0 && gx < BEVW) {
                x = in[(size_t)cg * SZC + gy * BEVW + gx];
                if (FUSE) x = fmaxf(fmaf(x, ab[2 * cg], ab[2 * cg + 1]), 0.0f);
            }
            s_in[c][rem] = x;
        }
        __syncthreads();

#pragma unroll
        for (int icl = 0; icl < ICB; ++icl) {
            const int icg = ic0 + icl;
#pragma unroll
            for (int tap = 0; tap < 9; ++tap) {
                const int ky = tap / 3, kx = tap % 3;
                float x = s_in[icl][(v + ky) * 18 + u + kx];
                // block-uniform address -> scalar loads into SGPRs
                const float* wk = wt + ((size_t)(icg * 9 + tap) * COUT + oc0);
#pragma unroll
                for (int o = 0; o < OCG; ++o)
                    acc[o] = fmaf(x, wk[o], acc[o]);
            }
        }
    }

    const int ox = tx + u, oy = ty + v;
    if (ox < BEVW && oy < BEVW) {
#pragma unroll
        for (int o = 0; o < OCG; ++o)
            out[(size_t)(oc0 + o) * SZC + oy * BEVW + ox] = acc[o] + bias[oc0 + o];
    }
}

// ---- BN stats stage 1 (r5): per (channel, slice) f64 partials ------------
__global__ void k_bnstats1(const float* __restrict__ y, double* __restrict__ part) {
    const int c = blockIdx.x, s = blockIdx.y;
    const int lo = s * ((SZC + NSL - 1) / NSL);
    const int hi = min(lo + (SZC + NSL - 1) / NSL, SZC);
    const float* p = y + (size_t)c * SZC;
    double sm = 0.0, s2 = 0.0;
    for (int i = lo + threadIdx.x; i < hi; i += 256) {
        float v = p[i];
        sm += (double)v;
        s2 += (double)v * (double)v;
    }
    for (int off = 32; off; off >>= 1) {
        sm += __shfl_down(sm, off);
        s2 += __shfl_down(s2, off);
    }
    __shared__ double sh[8];
    int wid = threadIdx.x >> 6;
    if ((threadIdx.x & 63) == 0) { sh[wid * 2] = sm; sh[wid * 2 + 1] = s2; }
    __syncthreads();
    if (threadIdx.x == 0) {
        double S = 0.0, S2 = 0.0;
        for (int wv = 0; wv < 4; ++wv) { S += sh[wv * 2]; S2 += sh[wv * 2 + 1]; }
        part[(c * NSL + s) * 2]     = S;
        part[(c * NSL + s) * 2 + 1] = S2;
    }
}

// ---- BN stats stage 2: fold -> (A,B) affine; BN+ReLU = relu(A*x+B) -------
__global__ void k_bnstats2(const double* __restrict__ part, const float* __restrict__ g,
                           const float* __restrict__ beta, float* __restrict__ statsAB) {
    int c = threadIdx.x;
    double S = 0.0, S2 = 0.0;
    for (int s = 0; s < NSL; ++s) {
        S  += part[(c * NSL + s) * 2];
        S2 += part[(c * NSL + s) * 2 + 1];
    }
    double mu  = S / (double)SZC;
    double var = S2 / (double)SZC - mu * mu;
    double A = (1.0 / sqrt(var + 1e-5)) * (double)g[c];
    statsAB[2 * c]     = (float)A;
    statsAB[2 * c + 1] = (float)((double)beta[c] - mu * A);
}

// ---- final BN apply + ReLU ----------------------------------------------
__global__ void k_bnreluS(const float* __restrict__ y, const float* __restrict__ ab,
                          float* __restrict__ out) {
    int c = blockIdx.y;
    int i = blockIdx.x * blockDim.x + threadIdx.x;
    if (i >= SZC) return;
    size_t idx = (size_t)c * SZC + i;
    out[idx] = fmaxf(fmaf(y[idx], ab[2 * c], ab[2 * c + 1]), 0.0f);
}

// ---------------------------------------------------------------------------
extern "C" void kernel_launch(void* const* d_in, const int* in_sizes, int n_in,
                              void* d_out, int out_size, void* d_ws, size_t ws_size,
                              hipStream_t stream) {
    const float4* pts = (const float4*)d_in[0];
    const float* w1 = (const float*)d_in[1];
    const float* b1 = (const float*)d_in[2];
    const float* g1 = (const float*)d_in[3];
    const float* be1 = (const float*)d_in[4];
    const float* w2 = (const float*)d_in[5];
    const float* b2 = (const float*)d_in[6];
    const float* g2 = (const float*)d_in[7];
    const float* be2 = (const float*)d_in[8];
    const float* w3 = (const float*)d_in[9];
    const float* b3 = (const float*)d_in[10];
    const float* g3 = (const float*)d_in[11];
    const float* be3 = (const float*)d_in[12];

    float* ws = (float*)d_ws;
    const size_t wsf = ws_size / 4;

    // --- fixed tail at end of workspace ---
    constexpr size_t TAILF = 128 + 250000 + 64 + 128 + 128 + 2048 + 1152 + 18432 + 36864;
    float* tail = ws + (wsf - TAILF);
    unsigned* gcnt = (unsigned*)tail;
    float* bev = tail + 128;                  // 4*SZC
    float* st1 = bev + 4 * SZC;               // 64  (A,B per ch)
    float* st2 = st1 + 64;                    // 128
    float* st3 = st2 + 128;                   // 128
    double* part = (double*)(st3 + 128);      // 64*NSL*2 doubles = 2048 floats
    float* wt1 = st3 + 128 + 2048;            // 1152
    float* wt2 = wt1 + 1152;                  // 18432
    float* wt3 = wt2 + 18432;                 // 36864

    // --- dynamic region: recs, then activations alias (recs dead) ---
    unsigned long long* recs = (unsigned long long*)ws;   // 8,601,600 floats
    float* y1 = ws;                                       // 32*SZC
    float* y2 = ws + 2000000;                             // 64*SZC
    float* out = (float*)d_out;

    int n = in_sizes[0] / 4;                              // 5,000,000 points
    const int cellBlocks = (SZC + 255) / 256;

    // weight transposes
    k_wt<<<(32 * 4 * 9 + 255) / 256, 256, 0, stream>>>(w1, wt1, 4, 32);
    k_wt<<<(64 * 32 * 9 + 255) / 256, 256, 0, stream>>>(w2, wt2, 32, 64);
    k_wt<<<(64 * 64 * 9 + 255) / 256, 256, 0, stream>>>(w3, wt3, 64, 64);

    // points -> BEV
    k_initg<<<1, 128, 0, stream>>>(gcnt);
    k_bucket<<<NB, 256, 0, stream>>>(pts, n, recs, gcnt);
    k_reduce<<<NBKT, 1024, 0, stream>>>(recs, gcnt, bev);

    // layer 1: 4 -> 32 (raw conv out; BN1+ReLU consumed by conv2 staging)
    k_conv<4, 32, 4, 16, false><<<dim3(256, 2), 256, 0, stream>>>(bev, wt1, b1, nullptr, y1);
    k_bnstats1<<<dim3(32, NSL), 256, 0, stream>>>(y1, part);
    k_bnstats2<<<1, 32, 0, stream>>>(part, g1, be1, st1);

    // layer 2: 32 -> 64 (BN1+ReLU fused into staging)
    k_conv<32, 64, 8, 16, true><<<dim3(256, 4), 256, 0, stream>>>(y1, wt2, b2, st1, y2);
    k_bnstats1<<<dim3(64, NSL), 256, 0, stream>>>(y2, part);
    k_bnstats2<<<1, 64, 0, stream>>>(part, g2, be2, st2);

    // layer 3: 64 -> 64 (BN2+ReLU fused into staging; raw out -> d_out)
    k_conv<64, 64, 8, 16, true><<<dim3(256, 4), 256, 0, stream>>>(y2, wt3, b3, st2, out);
    k_bnstats1<<<dim3(64, NSL), 256, 0, stream>>>(out, part);
    k_bnstats2<<<1, 64, 0, stream>>>(part, g3, be3, st3);

    // final BN3 + ReLU in place
    k_bnreluS<<<dim3(cellBlocks, 64), 256, 0, stream>>>(out, st3, out);
}